// Round 2
// baseline (2000.642 us; speedup 1.0000x reference)
//
#include <hip/hip_runtime.h>

#define DI __device__ __forceinline__

typedef unsigned short u16;
typedef unsigned int u32;
typedef __bf16 bf16x8 __attribute__((ext_vector_type(8)));
typedef float f32x4 __attribute__((ext_vector_type(4)));

// Model dims
static constexpr int B = 256, Tn = 20, En = 96, Hn = 670, Vn = 10004;
static constexpr int HP = 672;            // padded hidden

DI float bf2f(u16 u) { union { u32 i; float f; } v; v.i = ((u32)u) << 16; return v.f; }
DI u16 f2bf(float f) {
    u32 u = __float_as_uint(f);
    u32 r = (u + 0x7FFFu + ((u >> 16) & 1u)) >> 16;
    return (u16)r;
}
DI float sigm(float x) { return 1.f / (1.f + __expf(-x)); }
DI float tanha(float x) {
    x = fminf(fmaxf(x, -15.f), 15.f);
    float e = __expf(2.f * x);
    return (e - 1.f) / (e + 1.f);
}
DI bf16x8 frag(const u16* p) { return *(const bf16x8*)p; }
DI f32x4 mfma16(bf16x8 a, bf16x8 b, f32x4 c) {
    return __builtin_amdgcn_mfma_f32_16x16x32_bf16(a, b, c, 0, 0, 0);
}
// flag-aware element loads (f=1 -> source is float32, f=0 -> bf16)
DI u16 ldw(const u16* src, long long i, int f) {
    return f ? f2bf(((const float*)src)[i]) : src[i];
}
DI float ldf(const u16* src, long long i, int f) {
    return f ? ((const float*)src)[i] : bf2f(src[i]);
}

struct Ptrs {
    const int* x;
    const u16 *emb, *g_wi, *g_wh, *g_bi, *g_bh, *l_wi, *l_wh, *l_bi, *l_bh;
    const u16 *gl1_w, *gl1_b, *ll1_w, *ll1_b, *gl2_w, *gl2_b, *ll2_w, *ll2_b;
    const u16 *p1_w, *p1_b, *p2_w, *p2_b, *p3_w, *p3_b, *p4_w, *p4_b, *pe_w, *pe_b;
    const u16 *q1_w, *q1_b, *q2_w, *q2_b, *q2e_w, *q2e_b, *q3_w, *q3_b, *q3e_w, *q3e_b;
    // scratch
    int  *flagp;  // [0] = 1 if inputs are float32
    u16 *embs;    // [T][B][96] bf16
    u16 *WgCat;   // [2][2680][768] bf16 : [wi(96) | wh(670) | pad]
    u16 *P1W;     // [512][1440] bf16
    u16 *W1C;     // [192][672] bf16
    u16 *W2C;     // [10112][192] bf16 : [gl2_w | ll2_w]
    float *BSUM;  // [2][2680] f32 bias sums
    u16 *hs;      // [5120][672] bf16 (row n = b*20+t)
    u16 *hcat;    // [2][B][1344] bf16 double-buffered
    u16 *uw;      // [5120][192] bf16
    float *ghf, *gcf, *lhf, *lc2, *gcm;
    float *L1out; // [B][500]
    float *sf;    // [5120][192]
    float *p2sbuf;// [5120][2]
    // normalized bf16 copies of small tensors
    u16 *n_p1b, *n_p2w, *n_p2b, *n_p3w, *n_p3b, *n_p4w, *n_p4b, *n_pew, *n_peb;
    u16 *n_gl1b, *n_ll1b, *n_gl2b, *n_ll2b;
    u16 *n_q1w, *n_q1b, *n_q2w, *n_q2b, *n_q2ew, *n_q2eb, *n_q3w, *n_q3b, *n_q3ew, *n_q3eb;
    u16 *out0, *out1;
    float *out0f, *out1f;
};

// ------------- detect input dtype -------------
__global__ __launch_bounds__(64) void k_detect(Ptrs p) {
    int lane = threadIdx.x;
    u32 d = ((const u32*)p.g_bi)[lane];   // first 64 dwords of g_bi
    u16 lo = (u16)(d & 0xffffu);
    int e = (lo >> 7) & 0xff;             // bf16 exponent field of the LOW u16
    unsigned long long m = __ballot(e >= 127);   // |x|>=1 impossible for bf16 N(0,.05) data
    if (lane == 0) p.flagp[0] = (m != 0ull) ? 1 : 0;
}

// ------------- normalize small tensors to bf16 scratch -------------
__global__ __launch_bounds__(256) void k_norm(Ptrs p) {
    const int f = p.flagp[0];
    int i = blockIdx.x * 256 + threadIdx.x;
    const u16* srcs[23] = {p.p1_b, p.p2_w, p.p2_b, p.p3_w, p.p3_b, p.p4_w, p.p4_b,
                           p.pe_w, p.pe_b, p.gl1_b, p.ll1_b, p.gl2_b, p.ll2_b,
                           p.q1_w, p.q1_b, p.q2_w, p.q2_b, p.q2e_w, p.q2e_b,
                           p.q3_w, p.q3_b, p.q3e_w, p.q3e_b};
    u16* dsts[23] = {p.n_p1b, p.n_p2w, p.n_p2b, p.n_p3w, p.n_p3b, p.n_p4w, p.n_p4b,
                     p.n_pew, p.n_peb, p.n_gl1b, p.n_ll1b, p.n_gl2b, p.n_ll2b,
                     p.n_q1w, p.n_q1b, p.n_q2w, p.n_q2b, p.n_q2ew, p.n_q2eb,
                     p.n_q3w, p.n_q3b, p.n_q3ew, p.n_q3eb};
    const int ns[23] = {500, 125000, 250, 25000, 100, 5000, 50, 100, 2, 96, 96, 10004, 10004,
                        14400, 75, 2250, 30, 60, 2, 300, 10, 20, 2};
    #pragma unroll 1
    for (int s = 0; s < 23; ++s) {
        if (i < ns[s]) { dsts[s][i] = ldw(srcs[s], i, f); return; }
        i -= ns[s];
    }
}

// ---------------- prep: gather embeddings, pack/pad weights ----------------
__global__ __launch_bounds__(256) void k_prep(Ptrs p) {
    const int f = p.flagp[0];
    int i = blockIdx.x * 256 + threadIdx.x;
    if (i < 491520) { // embs gather, elementwise
        int r = i / 96, j = i % 96;
        int t = r >> 8, b = r & 255;
        int idx = p.x[b * Tn + t];
        p.embs[r * 96 + j] = ldw(p.emb, (long long)idx * 96 + j, f);
        return;
    }
    i -= 491520;
    if (i < 2 * 2680 * 768) { // WgCat
        int z = i / (2680 * 768);
        int rem = i - z * (2680 * 768);
        int col = rem / 768, k = rem % 768;
        const u16* wi = z ? p.l_wi : p.g_wi;
        const u16* wh = z ? p.l_wh : p.g_wh;
        u16 v = 0;
        if (k < 96) v = ldw(wi, col * 96 + k, f);
        else { int j = k - 96; if (j < 670) v = ldw(wh, col * 670 + j, f); }
        p.WgCat[i] = v;
        return;
    }
    i -= 2 * 2680 * 768;
    if (i < 512 * 1440) { // P1W
        int col = i / 1440, k = i % 1440;
        u16 v = 0;
        if (col < 500) {
            if (k < 96) v = ldw(p.p1_w, col * 1436 + k, f);
            else if (k < 768) { int j = k - 96;  if (j < 670) v = ldw(p.p1_w, col * 1436 + 96 + j, f); }
            else              { int j = k - 768; if (j < 670) v = ldw(p.p1_w, col * 1436 + 766 + j, f); }
        }
        p.P1W[i] = v;
        return;
    }
    i -= 512 * 1440;
    if (i < 192 * 672) { // W1C
        int o = i / 672, h = i % 672;
        u16 v = 0;
        if (h < 670) v = (o < 96) ? ldw(p.gl1_w, o * 670 + h, f) : ldw(p.ll1_w, (o - 96) * 670 + h, f);
        p.W1C[i] = v;
        return;
    }
    i -= 192 * 672;
    if (i < 10112 * 192) { // W2C
        int v_ = i / 192, k = i % 192;
        u16 v = 0;
        if (v_ < Vn) v = (k < 96) ? ldw(p.gl2_w, v_ * 96 + k, f) : ldw(p.ll2_w, v_ * 96 + (k - 96), f);
        p.W2C[i] = v;
        return;
    }
    i -= 10112 * 192;
    if (i < 2 * 2680) { // BSUM
        int z = i / 2680, col = i % 2680;
        const u16* bi = z ? p.l_bi : p.g_bi;
        const u16* bh = z ? p.l_bh : p.g_bh;
        p.BSUM[i] = ldf(bi, col, f) + ldf(bh, col, f);
    }
}

// ------------- per-step: fused gates GEMM + LSTM elementwise -------------
__global__ __launch_bounds__(256) void k_gates(Ptrs p, int t) {
    const int jt = blockIdx.x;       // 0..20, 32 j per tile
    const int mt = blockIdx.y;       // 0..7,  32 rows per tile
    const int z  = blockIdx.z;
    const int row0 = mt * 32, j0 = jt * 32;
    const int tid = threadIdx.x, lane = tid & 63, wv = tid >> 6;

    __shared__ u16 Al[32 * 40];
    __shared__ u16 Wl[128 * 40];
    __shared__ float bs[128];

    if (tid < 128) {
        int gate = tid >> 5, jj = tid & 31, j = j0 + jj;
        bs[tid] = (j < Hn) ? p.BSUM[z * 2680 + gate * Hn + j] : 0.f;
    }
    const int cur = t & 1, prv = cur ^ 1;
    f32x4 acc[4] = {};
    const int mtw = wv & 1, jh = wv >> 1;

    for (int kc = 0; kc < 24; ++kc) {
        const int kb = kc * 32;
        __syncthreads();
        if (tid < 128) {
            int r = tid >> 2, k8 = (tid & 3) * 8, k = kb + k8;
            int b = row0 + r;
            uint4 val = {0, 0, 0, 0};
            if (k < 96) val = *(const uint4*)&p.embs[(t * 256 + b) * 96 + k];
            else if (t > 0) {
                int kk = k - 96;
                const u16* src = (z == 0) ? (p.hs + (b * Tn + (t - 1)) * HP + kk)
                                          : (p.hcat + prv * (B * 1344) + b * 1344 + 672 + kk);
                val = *(const uint4*)src;
            }
            *(uint4*)&Al[r * 40 + k8] = val;
        }
        #pragma unroll
        for (int it = 0; it < 2; ++it) {
            int idx = tid + it * 256;
            int ri = idx >> 2, k8 = (idx & 3) * 8;
            int gate = ri >> 5, jj = ri & 31, j = j0 + jj;
            uint4 val = {0, 0, 0, 0};
            if (j < Hn) val = *(const uint4*)&p.WgCat[(z * 2680 + gate * Hn + j) * 768 + kb + k8];
            *(uint4*)&Wl[ri * 40 + k8] = val;
        }
        __syncthreads();
        bf16x8 a = frag(&Al[(mtw * 16 + (lane & 15)) * 40 + (lane >> 4) * 8]);
        #pragma unroll
        for (int g = 0; g < 4; ++g) {
            int nt = g * 2 + jh;
            bf16x8 bb = frag(&Wl[(nt * 16 + (lane & 15)) * 40 + (lane >> 4) * 8]);
            acc[g] = mfma16(a, bb, acc[g]);
        }
    }
    const int q = lane >> 4;
    const int jj = jh * 16 + (lane & 15);
    const int j = j0 + jj;
    const bool valid = (j < Hn);
    #pragma unroll
    for (int r = 0; r < 4; ++r) {
        int b = row0 + mtw * 16 + q * 4 + r;
        float I = fminf(fmaxf(acc[0][r] + bs[jj], -30.f), 30.f);
        float F = fminf(fmaxf(acc[1][r] + bs[32 + jj], -30.f), 30.f);
        float G = fminf(fmaxf(acc[2][r] + bs[64 + jj], -30.f), 30.f);
        float O = fminf(fmaxf(acc[3][r] + bs[96 + jj], -30.f), 30.f);
        float cp = 0.f;
        if (valid && t > 0)
            cp = (z == 0) ? p.gcm[b * Hn + j] : p.lc2[prv * (B * Hn) + b * Hn + j];
        float c = sigm(F) * cp + sigm(I) * tanha(G);
        float h = sigm(O) * tanha(c);
        if (z == 0) {
            if (valid) { p.ghf[b * Hn + j] = h; p.gcf[b * Hn + j] = c; }
            p.hcat[cur * (B * 1344) + b * 1344 + j] = valid ? f2bf(h) : (u16)0;
        } else {
            if (valid) { p.lhf[b * Hn + j] = h; p.lc2[cur * (B * Hn) + b * Hn + j] = c; }
            p.hcat[cur * (B * 1344) + b * 1344 + 672 + j] = valid ? f2bf(h) : (u16)0;
        }
    }
}

// ------------- per-step: MLP layer 1 GEMM [256,1440]@[1440,512] -------------
__global__ __launch_bounds__(256) void k_mlp1(Ptrs p, int t) {
    const int col0 = blockIdx.x * 64;
    const int row0 = blockIdx.y * 32;
    const int tid = threadIdx.x, lane = tid & 63, wv = tid >> 6;
    __shared__ u16 Al[32 * 40];
    __shared__ u16 Wl[64 * 40];
    const int cur = t & 1;
    f32x4 acc[2] = {};
    const int mtw = wv & 1, nh = wv >> 1;
    for (int kc = 0; kc < 45; ++kc) {
        const int kb = kc * 32;
        __syncthreads();
        if (tid < 128) {
            int r = tid >> 2, k8 = (tid & 3) * 8, k = kb + k8;
            int b = row0 + r;
            uint4 val;
            if (k < 96) val = *(const uint4*)&p.embs[(t * 256 + b) * 96 + k];
            else        val = *(const uint4*)&p.hcat[cur * (B * 1344) + b * 1344 + (k - 96)];
            *(uint4*)&Al[r * 40 + k8] = val;
        }
        {
            int ri = tid >> 2, k8 = (tid & 3) * 8;
            *(uint4*)&Wl[ri * 40 + k8] = *(const uint4*)&p.P1W[(col0 + ri) * 1440 + kb + k8];
        }
        __syncthreads();
        bf16x8 a = frag(&Al[(mtw * 16 + (lane & 15)) * 40 + (lane >> 4) * 8]);
        #pragma unroll
        for (int s = 0; s < 2; ++s) {
            int nt = nh + s * 2;
            bf16x8 bb = frag(&Wl[(nt * 16 + (lane & 15)) * 40 + (lane >> 4) * 8]);
            acc[s] = mfma16(a, bb, acc[s]);
        }
    }
    const int q = lane >> 4;
    #pragma unroll
    for (int s = 0; s < 2; ++s) {
        int col = col0 + (nh + s * 2) * 16 + (lane & 15);
        if (col < 500) {
            float bias = bf2f(p.n_p1b[col]);
            #pragma unroll
            for (int r = 0; r < 4; ++r) {
                int b = row0 + mtw * 16 + q * 4 + r;
                p.L1out[b * 500 + col] = fmaxf(acc[s][r] + bias, 0.f);
            }
        }
    }
}

// ------------- per-step: MLP layers 2..5, softmax, mix, write hs/out1 -------------
__global__ __launch_bounds__(256) void k_rest(Ptrs p, int t) {
    const int b = blockIdx.x, tid = threadIdx.x;
    const int f = p.flagp[0];
    __shared__ float l1[500];
    __shared__ float h2s[250];
    __shared__ float h3s[100];
    __shared__ float h4s[50];
    __shared__ float pr[2];
    for (int i = tid; i < 125; i += 256)
        *(float4*)&l1[i * 4] = *(const float4*)&p.L1out[b * 500 + i * 4];
    __syncthreads();
    if (tid < 250) {
        const u16* wr = p.n_p2w + tid * 500;
        float s = 0.f;
        for (int k = 0; k < 500; k += 4) {
            uint2 u = *(const uint2*)&wr[k];
            s += l1[k]     * bf2f((u16)(u.x & 0xffff));
            s += l1[k + 1] * bf2f((u16)(u.x >> 16));
            s += l1[k + 2] * bf2f((u16)(u.y & 0xffff));
            s += l1[k + 3] * bf2f((u16)(u.y >> 16));
        }
        h2s[tid] = fmaxf(s + bf2f(p.n_p2b[tid]), 0.f);
    }
    __syncthreads();
    if (tid < 100) {
        const u16* wr = p.n_p3w + tid * 250;
        float s = 0.f;
        for (int k = 0; k < 250; k += 2) {
            u32 u = *(const u32*)&wr[k];
            s += h2s[k]     * bf2f((u16)(u & 0xffff));
            s += h2s[k + 1] * bf2f((u16)(u >> 16));
        }
        h3s[tid] = fmaxf(s + bf2f(p.n_p3b[tid]), 0.f);
    }
    __syncthreads();
    if (tid < 50) {
        const u16* wr = p.n_p4w + tid * 100;
        float s = 0.f;
        for (int k = 0; k < 100; k += 4) {
            uint2 u = *(const uint2*)&wr[k];
            s += h3s[k]     * bf2f((u16)(u.x & 0xffff));
            s += h3s[k + 1] * bf2f((u16)(u.x >> 16));
            s += h3s[k + 2] * bf2f((u16)(u.y & 0xffff));
            s += h3s[k + 3] * bf2f((u16)(u.y >> 16));
        }
        h4s[tid] = fmaxf(s + bf2f(p.n_p4b[tid]), 0.f);
    }
    __syncthreads();
    if (tid == 0) {
        float e0 = bf2f(p.n_peb[0]), e1 = bf2f(p.n_peb[1]);
        for (int k = 0; k < 50; ++k) {
            e0 += h4s[k] * bf2f(p.n_pew[k]);
            e1 += h4s[k] * bf2f(p.n_pew[50 + k]);
        }
        float m = fmaxf(e0, e1);
        float a0 = __expf(e0 - m), a1 = __expf(e1 - m);
        float inv = 1.f / (a0 + a1);
        pr[0] = a0 * inv; pr[1] = a1 * inv;
    }
    __syncthreads();
    float p0 = pr[0], p1 = pr[1];
    const int cur = t & 1;
    for (int j = tid; j < HP; j += 256) {
        u16 hv = 0;
        if (j < Hn) {
            float gm = p0 * p.lhf[b * Hn + j] + p1 * p.ghf[b * Hn + j];
            float cm = p0 * p.lc2[cur * (B * Hn) + b * Hn + j] + p1 * p.gcf[b * Hn + j];
            p.gcm[b * Hn + j] = cm;
            hv = f2bf(gm);
        }
        p.hs[(b * Tn + t) * HP + j] = hv;
    }
    if (tid < 40) {
        long long idx = b * 880 + t * 40 + tid;
        if (f) p.out1f[idx] = pr[tid & 1]; else p.out1[idx] = f2bf(pr[tid & 1]);
    }
}

// ------------- post: sf = hs @ [gl1;ll1]^T + bias  ([5120,672]@[672,192]) -------------
__global__ __launch_bounds__(256) void k_sf(Ptrs p) {
    const int col0 = blockIdx.x * 64;
    const int row0 = blockIdx.y * 64;
    const int tid = threadIdx.x, lane = tid & 63, wv = tid >> 6;
    __shared__ u16 Al[64 * 40];
    __shared__ u16 Wl[64 * 40];
    f32x4 acc[4] = {};
    for (int kc = 0; kc < 21; ++kc) {
        const int kb = kc * 32;
        __syncthreads();
        {
            int r = tid >> 2, k8 = (tid & 3) * 8;
            *(uint4*)&Al[r * 40 + k8] = *(const uint4*)&p.hs[(row0 + r) * HP + kb + k8];
            *(uint4*)&Wl[r * 40 + k8] = *(const uint4*)&p.W1C[(col0 + r) * HP + kb + k8];
        }
        __syncthreads();
        bf16x8 a = frag(&Al[(wv * 16 + (lane & 15)) * 40 + (lane >> 4) * 8]);
        #pragma unroll
        for (int nt = 0; nt < 4; ++nt) {
            bf16x8 bb = frag(&Wl[(nt * 16 + (lane & 15)) * 40 + (lane >> 4) * 8]);
            acc[nt] = mfma16(a, bb, acc[nt]);
        }
    }
    const int q = lane >> 4;
    #pragma unroll
    for (int nt = 0; nt < 4; ++nt) {
        int col = col0 + nt * 16 + (lane & 15);
        float bias = bf2f(col < 96 ? p.n_gl1b[col] : p.n_ll1b[col - 96]);
        #pragma unroll
        for (int r = 0; r < 4; ++r) {
            int row = row0 + wv * 16 + q * 4 + r;
            p.sf[row * 192 + col] = acc[nt][r] + bias;
        }
    }
}

// ------------- post: per-batch q-chain, softmaxes, u/w, out1 rows 20/21 -------------
__global__ __launch_bounds__(256) void k_qchain(Ptrs p) {
    const int b = blockIdx.x, tid = threadIdx.x;
    const int f = p.flagp[0];
    __shared__ float sfl[20 * 192];
    __shared__ float h1[20][80];
    __shared__ float h2[20][32];
    __shared__ float h3[20][12];
    __shared__ float yv[20][2];
    __shared__ float zv[20][2];
    __shared__ float p1s[20][2];
    __shared__ float p2sl[20][2];
    for (int i = tid; i < 960; i += 256)
        *(float4*)&sfl[i * 4] = *(const float4*)&p.sf[b * 3840 + i * 4];
    __syncthreads();
    for (int u = tid; u < 1500; u += 256) {
        int row = u / 75, o = u % 75;
        const u16* wr = p.n_q1w + o * 192;
        const float* sr = &sfl[row * 192];
        float s = bf2f(p.n_q1b[o]);
        for (int k = 0; k < 192; k += 4) {
            uint2 w = *(const uint2*)&wr[k];
            s += sr[k]     * bf2f((u16)(w.x & 0xffff));
            s += sr[k + 1] * bf2f((u16)(w.x >> 16));
            s += sr[k + 2] * bf2f((u16)(w.y & 0xffff));
            s += sr[k + 3] * bf2f((u16)(w.y >> 16));
        }
        h1[row][o] = fmaxf(s, 0.f);
    }
    __syncthreads();
    for (int u = tid; u < 600; u += 256) {
        int row = u / 30, o = u % 30;
        const u16* wr = p.n_q2w + o * 75;
        float s = bf2f(p.n_q2b[o]);
        for (int k = 0; k < 75; ++k) s += h1[row][k] * bf2f(wr[k]);
        h2[row][o] = fmaxf(s, 0.f);
    }
    __syncthreads();
    if (tid < 40) {
        int row = tid >> 1, o = tid & 1;
        const u16* wr = p.n_q2ew + o * 30;
        float s = bf2f(p.n_q2eb[o]);
        for (int k = 0; k < 30; ++k) s += h2[row][k] * bf2f(wr[k]);
        yv[row][o] = fmaxf(s, 0.f);
    } else if (tid >= 56) {
        int u = tid - 56;  // 200 units
        int row = u / 10, o = u % 10;
        const u16* wr = p.n_q3w + o * 30;
        float s = bf2f(p.n_q3b[o]);
        for (int k = 0; k < 30; ++k) s += h2[row][k] * bf2f(wr[k]);
        h3[row][o] = fmaxf(s, 0.f);
    }
    __syncthreads();
    if (tid < 40) {
        int row = tid >> 1, o = tid & 1;
        const u16* wr = p.n_q3ew + o * 10;
        float s = bf2f(p.n_q3eb[o]);
        for (int k = 0; k < 10; ++k) s += h3[row][k] * bf2f(wr[k]);
        zv[row][o] = fmaxf(s, 0.f);
    } else if (tid >= 64 && tid < 84) {
        int row = tid - 64;
        float m = fmaxf(yv[row][0], yv[row][1]);
        float a0 = __expf(yv[row][0] - m), a1 = __expf(yv[row][1] - m);
        float inv = 1.f / (a0 + a1);
        p1s[row][0] = a0 * inv; p1s[row][1] = a1 * inv;
    }
    __syncthreads();
    if (tid < 20) {
        float m = fmaxf(zv[tid][0], zv[tid][1]);
        float a0 = __expf(zv[tid][0] - m), a1 = __expf(zv[tid][1] - m);
        float inv = 1.f / (a0 + a1);
        p2sl[tid][0] = a0 * inv; p2sl[tid][1] = a1 * inv;
        p.p2sbuf[(b * Tn + tid) * 2]     = a0 * inv;
        p.p2sbuf[(b * Tn + tid) * 2 + 1] = a1 * inv;
    } else if (tid >= 64 && tid < 104) {
        int row = (tid - 64) >> 1, c = (tid - 64) & 1;
        long long idx = b * 880 + 800 + row * 2 + c;
        if (f) p.out1f[idx] = p1s[row][c]; else p.out1[idx] = f2bf(p1s[row][c]);
    }
    __syncthreads();
    for (int u = tid; u < 1920; u += 256) {
        int row = u / 96, e = u % 96;
        float xm = p1s[row][0] * sfl[row * 192 + e] + p1s[row][1] * sfl[row * 192 + 96 + e];
        p.uw[(b * Tn + row) * 192 + e]      = f2bf(p2sl[row][0] * xm);
        p.uw[(b * Tn + row) * 192 + 96 + e] = f2bf(p2sl[row][1] * xm);
    }
    if (tid < 40) {
        int row = tid >> 1, c = tid & 1;
        long long idx = b * 880 + 840 + row * 2 + c;
        if (f) p.out1f[idx] = p2sl[row][c]; else p.out1[idx] = f2bf(p2sl[row][c]);
    }
}

// ------------- final GEMM: C[v,(b,t)] = W2C[v,:]·uw[n,:], K=192, out [B][V][T] -------------
__global__ __launch_bounds__(256) void k_final(Ptrs p) {
    const int n0 = blockIdx.x * 64;   // 80 blocks
    const int v0 = blockIdx.y * 128;  // 79 blocks
    const int tid = threadIdx.x, lane = tid & 63, wv = tid >> 6;
    const int f = p.flagp[0];
    __shared__ u16 Wl[128 * 104];
    __shared__ u16 Ul[64 * 104];
    f32x4 acc[2][4] = {};
    const int m = lane & 15, q = lane >> 4;
    for (int kc = 0; kc < 2; ++kc) {
        const int kb = kc * 96;
        __syncthreads();
        for (int i = tid; i < 1536; i += 256) {
            int ri = i / 12, k8 = (i % 12) * 8;
            *(uint4*)&Wl[ri * 104 + k8] = *(const uint4*)&p.W2C[(v0 + ri) * 192 + kb + k8];
        }
        for (int i = tid; i < 768; i += 256) {
            int ri = i / 12, k8 = (i % 12) * 8;
            *(uint4*)&Ul[ri * 104 + k8] = *(const uint4*)&p.uw[(n0 + ri) * 192 + kb + k8];
        }
        __syncthreads();
        #pragma unroll
        for (int ks = 0; ks < 3; ++ks) {
            int ko = ks * 32 + q * 8;
            bf16x8 a0 = frag(&Wl[(wv * 32 + m) * 104 + ko]);
            bf16x8 a1 = frag(&Wl[(wv * 32 + 16 + m) * 104 + ko]);
            #pragma unroll
            for (int ni = 0; ni < 4; ++ni) {
                bf16x8 bb = frag(&Ul[(ni * 16 + m) * 104 + ko]);
                acc[0][ni] = mfma16(a0, bb, acc[0][ni]);
                acc[1][ni] = mfma16(a1, bb, acc[1][ni]);
            }
        }
    }
    #pragma unroll
    for (int ni = 0; ni < 4; ++ni) {
        int n = n0 + ni * 16 + m;
        int bb = n / 20, tt = n % 20;
        float s0 = p.p2sbuf[n * 2], s1 = p.p2sbuf[n * 2 + 1];
        size_t base = (size_t)bb * 200080 + tt;
        #pragma unroll
        for (int mi = 0; mi < 2; ++mi) {
            #pragma unroll
            for (int r = 0; r < 4; ++r) {
                int v = v0 + wv * 32 + mi * 16 + q * 4 + r;
                if (v < Vn) {
                    float val = acc[mi][ni][r] + s0 * bf2f(p.n_gl2b[v]) + s1 * bf2f(p.n_ll2b[v]);
                    size_t idx = base + (size_t)v * 20;
                    if (f) p.out0f[idx] = val; else p.out0[idx] = f2bf(val);
                }
            }
        }
    }
}

extern "C" void kernel_launch(void* const* d_in, const int* in_sizes, int n_in,
                              void* d_out, int out_size, void* d_ws, size_t ws_size,
                              hipStream_t stream) {
    Ptrs p;
    p.x    = (const int*)d_in[0];
    p.emb  = (const u16*)d_in[1];
    p.g_wi = (const u16*)d_in[2];  p.g_wh = (const u16*)d_in[3];
    p.g_bi = (const u16*)d_in[4];  p.g_bh = (const u16*)d_in[5];
    p.l_wi = (const u16*)d_in[6];  p.l_wh = (const u16*)d_in[7];
    p.l_bi = (const u16*)d_in[8];  p.l_bh = (const u16*)d_in[9];
    p.gl1_w = (const u16*)d_in[10]; p.gl1_b = (const u16*)d_in[11];
    p.ll1_w = (const u16*)d_in[12]; p.ll1_b = (const u16*)d_in[13];
    p.gl2_w = (const u16*)d_in[14]; p.gl2_b = (const u16*)d_in[15];
    p.ll2_w = (const u16*)d_in[16]; p.ll2_b = (const u16*)d_in[17];
    p.p1_w = (const u16*)d_in[18]; p.p1_b = (const u16*)d_in[19];
    p.p2_w = (const u16*)d_in[20]; p.p2_b = (const u16*)d_in[21];
    p.p3_w = (const u16*)d_in[22]; p.p3_b = (const u16*)d_in[23];
    p.p4_w = (const u16*)d_in[24]; p.p4_b = (const u16*)d_in[25];
    p.pe_w = (const u16*)d_in[26]; p.pe_b = (const u16*)d_in[27];
    p.q1_w = (const u16*)d_in[28]; p.q1_b = (const u16*)d_in[29];
    p.q2_w = (const u16*)d_in[30]; p.q2_b = (const u16*)d_in[31];
    p.q2e_w = (const u16*)d_in[32]; p.q2e_b = (const u16*)d_in[33];
    p.q3_w = (const u16*)d_in[34]; p.q3_b = (const u16*)d_in[35];
    p.q3e_w = (const u16*)d_in[36]; p.q3e_b = (const u16*)d_in[37];

    char* w = (char*)d_ws;
    auto carve = [&](size_t bytes) { char* r = w; w += (bytes + 255) & ~(size_t)255; return r; };
    p.flagp  = (int*)carve(256);
    p.embs   = (u16*)carve((size_t)20 * 256 * 96 * 2);
    p.WgCat  = (u16*)carve((size_t)2 * 2680 * 768 * 2);
    p.P1W    = (u16*)carve((size_t)512 * 1440 * 2);
    p.W1C    = (u16*)carve((size_t)192 * 672 * 2);
    p.W2C    = (u16*)carve((size_t)10112 * 192 * 2);
    p.BSUM   = (float*)carve((size_t)2 * 2680 * 4);
    p.hs     = (u16*)carve((size_t)5120 * 672 * 2);
    p.hcat   = (u16*)carve((size_t)2 * 256 * 1344 * 2);
    p.uw     = (u16*)carve((size_t)5120 * 192 * 2);
    p.ghf    = (float*)carve((size_t)256 * 670 * 4);
    p.gcf    = (float*)carve((size_t)256 * 670 * 4);
    p.lhf    = (float*)carve((size_t)256 * 670 * 4);
    p.lc2    = (float*)carve((size_t)2 * 256 * 670 * 4);
    p.gcm    = (float*)carve((size_t)256 * 670 * 4);
    p.L1out  = (float*)carve((size_t)256 * 500 * 4);
    p.sf     = (float*)carve((size_t)5120 * 192 * 4);
    p.p2sbuf = (float*)carve((size_t)5120 * 2 * 4);
    p.n_p1b = (u16*)carve(500 * 2);   p.n_p2w = (u16*)carve(125000 * 2);
    p.n_p2b = (u16*)carve(250 * 2);   p.n_p3w = (u16*)carve(25000 * 2);
    p.n_p3b = (u16*)carve(100 * 2);   p.n_p4w = (u16*)carve(5000 * 2);
    p.n_p4b = (u16*)carve(50 * 2);    p.n_pew = (u16*)carve(100 * 2);
    p.n_peb = (u16*)carve(2 * 2);
    p.n_gl1b = (u16*)carve(96 * 2);   p.n_ll1b = (u16*)carve(96 * 2);
    p.n_gl2b = (u16*)carve(10004 * 2); p.n_ll2b = (u16*)carve(10004 * 2);
    p.n_q1w = (u16*)carve(14400 * 2); p.n_q1b = (u16*)carve(75 * 2);
    p.n_q2w = (u16*)carve(2250 * 2);  p.n_q2b = (u16*)carve(30 * 2);
    p.n_q2ew = (u16*)carve(60 * 2);   p.n_q2eb = (u16*)carve(2 * 2);
    p.n_q3w = (u16*)carve(300 * 2);   p.n_q3b = (u16*)carve(10 * 2);
    p.n_q3ew = (u16*)carve(20 * 2);   p.n_q3eb = (u16*)carve(2 * 2);
    p.out0 = (u16*)d_out;
    p.out1 = p.out0 + 51220480;
    p.out0f = (float*)d_out;
    p.out1f = p.out0f + 51220480;

    k_detect<<<1, 64, 0, stream>>>(p);
    k_norm<<<756, 256, 0, stream>>>(p);
    k_prep<<<28990, 256, 0, stream>>>(p);
    for (int t = 0; t < 20; ++t) {
        k_gates<<<dim3(21, 8, 2), 256, 0, stream>>>(p, t);
        k_mlp1<<<dim3(8, 8), 256, 0, stream>>>(p, t);
        k_rest<<<256, 256, 0, stream>>>(p, t);
    }
    k_sf<<<dim3(3, 80), 256, 0, stream>>>(p);
    k_qchain<<<256, 256, 0, stream>>>(p);
    k_final<<<dim3(80, 79), 256, 0, stream>>>(p);
}